// Round 13
// baseline (530.192 us; speedup 1.0000x reference)
//
#include <hip/hip_runtime.h>
#include <math.h>

#define NNODES 100000
#define BSHIFT 9
#define NBKT ((NNODES + (1 << BSHIFT) - 1) >> BSHIFT)   // 196 buckets of 512 nodes
#define CAPB 10240                                       // expected 8163 + 23 sigma
#define CHUNK 2048

typedef _Float16 f16x8 __attribute__((ext_vector_type(8)));
typedef _Float16 f16x2 __attribute__((ext_vector_type(2)));
typedef float f32x4 __attribute__((ext_vector_type(4)));

// ---------------- phase 1: bin edges by dst bucket (packed 4B/edge) ---------
// packed = (dst&511)<<17 | src   (src < 2^17)
__global__ __launch_bounds__(256) void bin_kernel(
        const int* __restrict__ eidx, int E,
        unsigned* __restrict__ bedge, int* __restrict__ bcur) {
    __shared__ int hist[256];
    __shared__ int scanx[256];
    __shared__ int gbase[256];
    __shared__ unsigned stage[CHUNK];
    int tid = threadIdx.x;
    int base = blockIdx.x * CHUNK;
    if (base >= E) return;
    int m = min(CHUNK, E - base);
    hist[tid] = 0;
    __syncthreads();
    unsigned pk[8];
    int b[8], r[8];
#pragma unroll
    for (int j = 0; j < 8; ++j) {
        int rel = j * 256 + tid;
        bool ok = rel < m;
        int e = base + (ok ? rel : 0);
        int s = eidx[e];
        int d = eidx[E + e];
        b[j] = d >> BSHIFT;
        pk[j] = ((unsigned)(d & ((1 << BSHIFT) - 1)) << 17) | (unsigned)s;
        r[j] = ok ? atomicAdd(&hist[b[j]], 1) : -1;
    }
    __syncthreads();
    int h = hist[tid];
    scanx[tid] = h;
    __syncthreads();
    for (int st = 1; st < 256; st <<= 1) {
        int y = (tid >= st) ? scanx[tid - st] : 0;
        __syncthreads();
        scanx[tid] += y;
        __syncthreads();
    }
    int excl = scanx[tid] - h;
    if (h > 0) gbase[tid] = atomicAdd(&bcur[tid], h);
    __syncthreads();
    scanx[tid] = excl;
    __syncthreads();
#pragma unroll
    for (int j = 0; j < 8; ++j)
        if (r[j] >= 0) stage[scanx[b[j]] + r[j]] = pk[j];
    __syncthreads();
    for (int i = tid; i < m; i += 256) {
        int lo = 0, hi = NBKT - 1;
        while (lo < hi) {
            int mid = (lo + hi + 1) >> 1;
            if (scanx[mid] <= i) lo = mid; else hi = mid - 1;
        }
        int idx = gbase[lo] + (i - scanx[lo]);
        if (idx < CAPB) bedge[(size_t)lo * CAPB + idx] = stage[i];
    }
}

// ---------------- phase 2a: per-node counts from binned edges ---------------
__global__ __launch_bounds__(512) void count2_kernel(
        const unsigned* __restrict__ bedge, const int* __restrict__ bcur,
        int* __restrict__ counts, int n) {
    __shared__ int h[512];
    int b = blockIdx.x;
    int tid = threadIdx.x;
    h[tid] = 0;
    __syncthreads();
    int cnt = min(bcur[b], CAPB);
    const unsigned* e = bedge + (size_t)b * CAPB;
    for (int i = tid; i < cnt; i += 512) atomicAdd(&h[e[i] >> 17], 1);
    __syncthreads();
    int node = b * 512 + tid;
    if (node < n) counts[node] = h[tid];
}

// dis[i] = rsqrt(deg+1) for i<n; dis[n] = 0 (dummy node for pad slots)
__global__ void dis_kernel(const int* __restrict__ counts, float* __restrict__ dis, int n) {
    int i = blockIdx.x * 256 + threadIdx.x;
    if (i < n) dis[i] = rsqrtf((float)(counts[i] + 1));
    else if (i == n) dis[i] = 0.f;
}

// exclusive scan of PADDED counts -> offs; 1024 elements per block
__global__ void scan_local(const int* __restrict__ counts, int* __restrict__ offs,
                           int* __restrict__ bsums, int n) {
    __shared__ int tsum[256];
    int t = threadIdx.x;
    int base = blockIdx.x * 1024 + t * 4;
    int v0 = (base + 0 < n) ? ((counts[base + 0] + 7) & ~7) : 0;
    int v1 = (base + 1 < n) ? ((counts[base + 1] + 7) & ~7) : 0;
    int v2 = (base + 2 < n) ? ((counts[base + 2] + 7) & ~7) : 0;
    int v3 = (base + 3 < n) ? ((counts[base + 3] + 7) & ~7) : 0;
    tsum[t] = v0 + v1 + v2 + v3;
    __syncthreads();
    for (int d = 1; d < 256; d <<= 1) {
        int x = tsum[t];
        int y = (t >= d) ? tsum[t - d] : 0;
        __syncthreads();
        tsum[t] = x + y;
        __syncthreads();
    }
    int prev = (t > 0) ? tsum[t - 1] : 0;
    if (base + 0 < n) offs[base + 0] = prev;
    if (base + 1 < n) offs[base + 1] = prev + v0;
    if (base + 2 < n) offs[base + 2] = prev + v0 + v1;
    if (base + 3 < n) offs[base + 3] = prev + v0 + v1 + v2;
    if (t == 255) bsums[blockIdx.x] = tsum[255];
}

__global__ void scan_bsums(int* __restrict__ bsums, int nb) {
    __shared__ int s[128];
    int t = threadIdx.x;
    s[t] = (t < nb) ? bsums[t] : 0;
    __syncthreads();
    for (int d = 1; d < 128; d <<= 1) {
        int x = s[t];
        int y = (t >= d) ? s[t - d] : 0;
        __syncthreads();
        s[t] = x + y;
        __syncthreads();
    }
    int excl = (t > 0) ? s[t - 1] : 0;
    if (t < nb) bsums[t] = excl;
}

__global__ void add_base(int* __restrict__ offs, const int* __restrict__ bsums, int n) {
    int i = blockIdx.x * 256 + threadIdx.x;
    if (i < n) offs[i] += bsums[i >> 10];
}

// ---------------- phase 2b: bucket-local CSR fill (LDS cursors) -------------
__global__ __launch_bounds__(512) void fill2_kernel(
        const unsigned* __restrict__ bedge, const int* __restrict__ bcur,
        const int* __restrict__ offs, int* __restrict__ csrc, int n) {
    __shared__ int lofs[512];
    __shared__ int lcur[512];
    int b = blockIdx.x;
    int tid = threadIdx.x;
    int node = b * 512 + tid;
    lofs[tid] = (node < n) ? offs[node] : 0;
    lcur[tid] = 0;
    __syncthreads();
    int cnt = min(bcur[b], CAPB);
    const unsigned* e = bedge + (size_t)b * CAPB;
    for (int i = tid; i < cnt; i += 512) {
        unsigned pk = e[i];
        int dl = pk >> 17;
        int p = lofs[dl] + atomicAdd(&lcur[dl], 1);
        csrc[p] = (int)(pk & 0x1FFFFu);
    }
}

// fill pad tail of each segment with dummy node N (dis[N]=0 -> zero contribution)
__global__ void pad_kernel(const int* __restrict__ offs, const int* __restrict__ counts,
                           int* __restrict__ csrc, int n) {
    int i = blockIdx.x * 256 + threadIdx.x;
    if (i >= n) return;
    int c = counts[i];
    int p = (c + 7) & ~7;
    int o = offs[i];
    for (int j = c; j < p; ++j) csrc[o + j] = NNODES;
}

// zero dummy row N of gatherable buffers (row-major). Pad gathers read row N
// with norm 0 but fmaf(0, NaN)=NaN, so the row must be finite. Runs AFTER
// fill2 (hB aliases bedge).
__global__ void zdum_kernel(_Float16* __restrict__ x16, _Float16* __restrict__ hA,
                            _Float16* __restrict__ hB, int n) {
    int t = threadIdx.x;  // one block, 320 threads used
    if (t < 64) x16[(size_t)n * 64 + t] = (_Float16)0.f;
    else if (t < 192) hA[(size_t)n * 128 + (t - 64)] = (_Float16)0.f;
    else if (t < 320) hB[(size_t)n * 128 + (t - 192)] = (_Float16)0.f;
}

// x fp32 [N][50] -> fp16 [N][64] zero-padded (aligned gather + K=64 GEMM)
__global__ void cast_pad_kernel(const float* __restrict__ src, _Float16* __restrict__ dst,
                                int n) {
    int t = blockIdx.x * 256 + threadIdx.x;
    if (t >= n * 32) return;
    int node = t >> 5;
    int cp = t & 31;
    int c = cp * 2;
    float v0 = (c < 50) ? src[(size_t)node * 50 + c] : 0.f;
    float v1 = (c + 1 < 50) ? src[(size_t)node * 50 + c + 1] : 0.f;
    f16x2 h;
    h.x = (_Float16)v0;
    h.y = (_Float16)v1;
    *(f16x2*)&dst[(size_t)node * 64 + c] = h;
}

// ---------------- W -> per-lane fragment order (fp16), once per launch ------
__global__ void wfrag_kernel(const float* __restrict__ W, f16x8* __restrict__ frag,
                             int FIN, int FOUT, int KCN, int CTN) {
    int idx = blockIdx.x * 256 + threadIdx.x;
    int tot = KCN * CTN * 64;
    if (idx >= tot) return;
    int lane = idx & 63;
    int ct = (idx >> 6) % CTN;
    int kc = (idx >> 6) / CTN;
    int c = ct * 16 + (lane & 15);
    int kb = kc * 32 + (lane >> 4) * 8;
    f16x8 v;
#pragma unroll
    for (int j = 0; j < 8; ++j) {
        int k = kb + j;
        float w = (k < FIN && c < FOUT) ? W[(size_t)k * FOUT + c] : 0.f;
        v[j] = (_Float16)w;
    }
    frag[idx] = v;
}

// ---------------- fused aggregate + MFMA GEMM + bias + activation -----------
// Round-12 structure (block = 16 nodes, 4 waves, XOR-swizzled 16xK LDS tile,
// one barrier, per-wave 2-column-tile GEMM) with FULL 4-NODE INTERLEAVE:
// each wave walks all 4 of its nodes' edge lists simultaneously -> 32
// independent row-gathers per iteration. __launch_bounds__(256,4) raises the
// VGPR cap to 128 so the loads actually stay in flight. Shorter lists re-read
// their group 0 with norm forced to 0 (exact no-op, reads in-segment).
// Per-node accumulation order identical to round 12 -> bit-identical output.
// Requires n % 16 == 0. ACT: 0=relu, 1=sigmoid.
template <int KCN, int ACT, typename OT>
__global__ __launch_bounds__(256, 4) void fused_kernel(
        const f16x2* __restrict__ in, const int* __restrict__ offs,
        const int* __restrict__ counts, const int* __restrict__ csrc,
        const float* __restrict__ dis, const f16x8* __restrict__ wfrag,
        const float* __restrict__ bias, int fout,
        OT* __restrict__ out, int ldo, int n) {
    constexpr int K = KCN * 32;
    constexpr int ROWB = K * 2;   // bytes per LDS row
    constexpr int HW = K / 2;     // f16x2 per row
    __shared__ __align__(16) unsigned char sA[16 * ROWB];
    int tid = threadIdx.x;
    int wv = tid >> 6, lane = tid & 63;
    int nb = blockIdx.x * 16;
    bool act = lane < HW;
    int n0 = nb + wv * 4;

    float dd[4], ax[4], ay[4];
    int off[4], pc[4];
#pragma unroll
    for (int k = 0; k < 4; ++k) {
        dd[k] = dis[n0 + k];
        off[k] = offs[n0 + k];
        pc[k] = (counts[n0 + k] + 7) & ~7;
        ax[k] = 0.f;
        ay[k] = 0.f;
        if (act) {
            f16x2 sv = in[(size_t)(n0 + k) * HW + lane];
            ax[k] = dd[k] * dd[k] * (float)sv.x;
            ay[k] = dd[k] * dd[k] * (float)sv.y;
        }
    }
    int pmax = max(max(pc[0], pc[1]), max(pc[2], pc[3]));

    for (int j = 0; j < pmax; j += 8) {
        int4 i0[4], i1[4];
        float m[4];
#pragma unroll
        for (int k = 0; k < 4; ++k) {
            bool g = j < pc[k];
            int b = off[k] + (g ? j : 0);   // !g: re-read group 0, norm=0
            m[k] = g ? dd[k] : 0.f;
            i0[k] = *(const int4*)&csrc[b];
            i1[k] = *(const int4*)&csrc[b + 4];
        }
#pragma unroll
        for (int k = 0; k < 4; ++k) {
            float u0 = dis[i0[k].x] * m[k], u1 = dis[i0[k].y] * m[k];
            float u2 = dis[i0[k].z] * m[k], u3 = dis[i0[k].w] * m[k];
            float u4 = dis[i1[k].x] * m[k], u5 = dis[i1[k].y] * m[k];
            float u6 = dis[i1[k].z] * m[k], u7 = dis[i1[k].w] * m[k];
            if (act) {
                f16x2 r0 = in[(size_t)i0[k].x * HW + lane];
                f16x2 r1 = in[(size_t)i0[k].y * HW + lane];
                f16x2 r2 = in[(size_t)i0[k].z * HW + lane];
                f16x2 r3 = in[(size_t)i0[k].w * HW + lane];
                f16x2 r4 = in[(size_t)i1[k].x * HW + lane];
                f16x2 r5 = in[(size_t)i1[k].y * HW + lane];
                f16x2 r6 = in[(size_t)i1[k].z * HW + lane];
                f16x2 r7 = in[(size_t)i1[k].w * HW + lane];
                ax[k] = fmaf(u0, (float)r0.x, ax[k]); ay[k] = fmaf(u0, (float)r0.y, ay[k]);
                ax[k] = fmaf(u1, (float)r1.x, ax[k]); ay[k] = fmaf(u1, (float)r1.y, ay[k]);
                ax[k] = fmaf(u2, (float)r2.x, ax[k]); ay[k] = fmaf(u2, (float)r2.y, ay[k]);
                ax[k] = fmaf(u3, (float)r3.x, ax[k]); ay[k] = fmaf(u3, (float)r3.y, ay[k]);
                ax[k] = fmaf(u4, (float)r4.x, ax[k]); ay[k] = fmaf(u4, (float)r4.y, ay[k]);
                ax[k] = fmaf(u5, (float)r5.x, ax[k]); ay[k] = fmaf(u5, (float)r5.y, ay[k]);
                ax[k] = fmaf(u6, (float)r6.x, ax[k]); ay[k] = fmaf(u6, (float)r6.y, ay[k]);
                ax[k] = fmaf(u7, (float)r7.x, ax[k]); ay[k] = fmaf(u7, (float)r7.y, ay[k]);
            }
        }
    }

    if (act) {
#pragma unroll
        for (int k = 0; k < 4; ++k) {
            int r = wv * 4 + k;
            f16x2 o;
            o.x = (_Float16)ax[k];
            o.y = (_Float16)ay[k];
            *(f16x2*)(sA + r * ROWB + ((lane * 4) ^ ((r & 7) << 4))) = o;
        }
    }
    __syncthreads();

    // ---- phase 2: GEMM (per-wave 2 column tiles of 16) ----
    int r = lane & 15, g = lane >> 4;
    f32x4 acc[2];
    acc[0] = (f32x4){0.f, 0.f, 0.f, 0.f};
    acc[1] = (f32x4){0.f, 0.f, 0.f, 0.f};
#pragma unroll
    for (int kc = 0; kc < KCN; ++kc) {
        f16x8 a = *(const f16x8*)(sA + r * ROWB + ((kc * 64 + g * 16) ^ ((r & 7) << 4)));
        f16x8 b0 = wfrag[(size_t)(kc * 8 + wv * 2 + 0) * 64 + lane];
        f16x8 b1 = wfrag[(size_t)(kc * 8 + wv * 2 + 1) * 64 + lane];
        acc[0] = __builtin_amdgcn_mfma_f32_16x16x32_f16(a, b0, acc[0], 0, 0, 0);
        acc[1] = __builtin_amdgcn_mfma_f32_16x16x32_f16(a, b1, acc[1], 0, 0, 0);
    }
#pragma unroll
    for (int c = 0; c < 2; ++c) {
        int col = (wv * 2 + c) * 16 + r;
        if (col >= fout) continue;
        float bv = bias[col];
#pragma unroll
        for (int q = 0; q < 4; ++q) {
            int orow = nb + g * 4 + q;
            float v = acc[c][q] + bv;
            if (ACT == 0) v = fmaxf(v, 0.f);
            else v = 1.f / (1.f + __expf(-v));
            out[(size_t)orow * ldo + col] = (OT)v;
        }
    }
}

extern "C" void kernel_launch(void* const* d_in, const int* in_sizes, int n_in,
                              void* d_out, int out_size, void* d_ws, size_t ws_size,
                              hipStream_t stream) {
    const float* x = (const float*)d_in[0];
    const int* eidx = (const int*)d_in[1];
    const float* W1 = (const float*)d_in[2];
    const float* b1 = (const float*)d_in[3];
    const float* W2 = (const float*)d_in[4];
    const float* b2 = (const float*)d_in[5];
    const float* W3 = (const float*)d_in[6];
    const float* b3 = (const float*)d_in[7];
    const float* W4 = (const float*)d_in[8];
    const float* b4 = (const float*)d_in[9];
    float* out = (float*)d_out;

    const int N = NNODES;
    const int E = in_sizes[1] / 2;
    const size_t PE = (size_t)E + 8u * N;

    char* ws = (char*)d_ws;
    size_t off = 0;
    auto alloc = [&](size_t bytes) -> char* {
        char* p = ws + off;
        off = (off + bytes + 255) & ~(size_t)255;
        return p;
    };
    float* dis = (float*)alloc((size_t)(N + 1) * 4);
    int* counts = (int*)alloc((size_t)N * 4);
    int* offs = (int*)alloc((size_t)N * 4);
    int* bsums = (int*)alloc(128 * 4);
    int* bcur = (int*)alloc(256 * 4);
    int* csrc = (int*)alloc(PE * 4);
    _Float16* hA = (_Float16*)alloc((size_t)(N + 1) * 128 * 2);
    _Float16* hB = (_Float16*)alloc((size_t)(N + 1) * 128 * 2);
    _Float16* x16 = (_Float16*)alloc((size_t)(N + 1) * 64 * 2);
    f16x8* wf1 = (f16x8*)alloc((size_t)2 * 8 * 64 * 16);
    f16x8* wf2 = (f16x8*)alloc((size_t)4 * 8 * 64 * 16);
    f16x8* wf3 = (f16x8*)alloc((size_t)4 * 8 * 64 * 16);
    f16x8* wf4 = (f16x8*)alloc((size_t)4 * 8 * 64 * 16);
    // bedge aliases hB: dead after fill2; hB fully rewritten by layer-2 GEMM
    // and its dummy row re-zeroed by zdum after fill2.
    unsigned* bedge = (unsigned*)hB;  // NBKT*CAPB*4 ~= 8MB < 25.6MB

    hipMemsetAsync(bcur, 0, 256 * 4, stream);

    // weight fragments (once per launch)
    wfrag_kernel<<<(2 * 8 * 64 + 255) / 256, 256, 0, stream>>>(W1, wf1, 50, 128, 2, 8);
    wfrag_kernel<<<(4 * 8 * 64 + 255) / 256, 256, 0, stream>>>(W2, wf2, 128, 128, 4, 8);
    wfrag_kernel<<<(4 * 8 * 64 + 255) / 256, 256, 0, stream>>>(W3, wf3, 128, 128, 4, 8);
    wfrag_kernel<<<(4 * 8 * 64 + 255) / 256, 256, 0, stream>>>(W4, wf4, 128, 121, 4, 8);

    // CSR build
    bin_kernel<<<(E + CHUNK - 1) / CHUNK, 256, 0, stream>>>(eidx, E, bedge, bcur);
    count2_kernel<<<NBKT, 512, 0, stream>>>(bedge, bcur, counts, N);
    dis_kernel<<<(N + 256) / 256, 256, 0, stream>>>(counts, dis, N);
    int nb = (N + 1023) / 1024;
    scan_local<<<nb, 256, 0, stream>>>(counts, offs, bsums, N);
    scan_bsums<<<1, 128, 0, stream>>>(bsums, nb);
    add_base<<<(N + 255) / 256, 256, 0, stream>>>(offs, bsums, N);
    fill2_kernel<<<NBKT, 512, 0, stream>>>(bedge, bcur, offs, csrc, N);
    pad_kernel<<<(N + 255) / 256, 256, 0, stream>>>(offs, counts, csrc, N);
    zdum_kernel<<<1, 320, 0, stream>>>(x16, hA, hB, N);  // after fill2 (bedge dead)

    cast_pad_kernel<<<(N * 32 + 255) / 256, 256, 0, stream>>>(x, x16, N);

    int fblocks = N / 16;  // 6250 blocks; block = 16 nodes, 4 waves
    // layer 1: fused agg(50->64-pad) + GEMM 64->128 + relu -> hA
    fused_kernel<2, 0, _Float16><<<fblocks, 256, 0, stream>>>(
        (const f16x2*)x16, offs, counts, csrc, dis, wf1, b1, 128, hA, 128, N);
    // layer 2: hA -> hB
    fused_kernel<4, 0, _Float16><<<fblocks, 256, 0, stream>>>(
        (const f16x2*)hA, offs, counts, csrc, dis, wf2, b2, 128, hB, 128, N);
    // layer 3: hB -> hA
    fused_kernel<4, 0, _Float16><<<fblocks, 256, 0, stream>>>(
        (const f16x2*)hB, offs, counts, csrc, dis, wf3, b3, 128, hA, 128, N);
    // layer 4: hA -> d_out (sigmoid, fp32, 121 cols)
    fused_kernel<4, 1, float><<<fblocks, 256, 0, stream>>>(
        (const f16x2*)hA, offs, counts, csrc, dis, wf4, b4, 121, out, 121, N);
}

// Round 14
// 509.558 us; speedup vs baseline: 1.0405x; 1.0405x over previous
//
#include <hip/hip_runtime.h>
#include <math.h>

#define NNODES 100000
#define BSHIFT 9
#define NBKT ((NNODES + (1 << BSHIFT) - 1) >> BSHIFT)   // 196 buckets of 512 nodes
#define CAPB 10240                                       // expected 8163 + 23 sigma
#define CHUNK 2048

typedef _Float16 f16x8 __attribute__((ext_vector_type(8)));
typedef _Float16 f16x2 __attribute__((ext_vector_type(2)));
typedef float f32x4 __attribute__((ext_vector_type(4)));

// ---------------- phase 1: bin edges by dst bucket (packed 4B/edge) ---------
// packed = (dst&511)<<17 | src   (src < 2^17)
__global__ __launch_bounds__(256) void bin_kernel(
        const int* __restrict__ eidx, int E,
        unsigned* __restrict__ bedge, int* __restrict__ bcur) {
    __shared__ int hist[256];
    __shared__ int scanx[256];
    __shared__ int gbase[256];
    __shared__ unsigned stage[CHUNK];
    int tid = threadIdx.x;
    int base = blockIdx.x * CHUNK;
    if (base >= E) return;
    int m = min(CHUNK, E - base);
    hist[tid] = 0;
    __syncthreads();
    unsigned pk[8];
    int b[8], r[8];
#pragma unroll
    for (int j = 0; j < 8; ++j) {
        int rel = j * 256 + tid;
        bool ok = rel < m;
        int e = base + (ok ? rel : 0);
        int s = eidx[e];
        int d = eidx[E + e];
        b[j] = d >> BSHIFT;
        pk[j] = ((unsigned)(d & ((1 << BSHIFT) - 1)) << 17) | (unsigned)s;
        r[j] = ok ? atomicAdd(&hist[b[j]], 1) : -1;
    }
    __syncthreads();
    int h = hist[tid];
    scanx[tid] = h;
    __syncthreads();
    for (int st = 1; st < 256; st <<= 1) {
        int y = (tid >= st) ? scanx[tid - st] : 0;
        __syncthreads();
        scanx[tid] += y;
        __syncthreads();
    }
    int excl = scanx[tid] - h;
    if (h > 0) gbase[tid] = atomicAdd(&bcur[tid], h);
    __syncthreads();
    scanx[tid] = excl;
    __syncthreads();
#pragma unroll
    for (int j = 0; j < 8; ++j)
        if (r[j] >= 0) stage[scanx[b[j]] + r[j]] = pk[j];
    __syncthreads();
    for (int i = tid; i < m; i += 256) {
        int lo = 0, hi = NBKT - 1;
        while (lo < hi) {
            int mid = (lo + hi + 1) >> 1;
            if (scanx[mid] <= i) lo = mid; else hi = mid - 1;
        }
        int idx = gbase[lo] + (i - scanx[lo]);
        if (idx < CAPB) bedge[(size_t)lo * CAPB + idx] = stage[i];
    }
}

// ---------------- phase 2a: per-node counts from binned edges ---------------
__global__ __launch_bounds__(512) void count2_kernel(
        const unsigned* __restrict__ bedge, const int* __restrict__ bcur,
        int* __restrict__ counts, int n) {
    __shared__ int h[512];
    int b = blockIdx.x;
    int tid = threadIdx.x;
    h[tid] = 0;
    __syncthreads();
    int cnt = min(bcur[b], CAPB);
    const unsigned* e = bedge + (size_t)b * CAPB;
    for (int i = tid; i < cnt; i += 512) atomicAdd(&h[e[i] >> 17], 1);
    __syncthreads();
    int node = b * 512 + tid;
    if (node < n) counts[node] = h[tid];
}

// dis[i] = rsqrt(deg+1) for i<n; dis[n] = 0 (dummy node for pad slots)
__global__ void dis_kernel(const int* __restrict__ counts, float* __restrict__ dis, int n) {
    int i = blockIdx.x * 256 + threadIdx.x;
    if (i < n) dis[i] = rsqrtf((float)(counts[i] + 1));
    else if (i == n) dis[i] = 0.f;
}

// exclusive scan of PADDED counts -> offs; 1024 elements per block
__global__ void scan_local(const int* __restrict__ counts, int* __restrict__ offs,
                           int* __restrict__ bsums, int n) {
    __shared__ int tsum[256];
    int t = threadIdx.x;
    int base = blockIdx.x * 1024 + t * 4;
    int v0 = (base + 0 < n) ? ((counts[base + 0] + 7) & ~7) : 0;
    int v1 = (base + 1 < n) ? ((counts[base + 1] + 7) & ~7) : 0;
    int v2 = (base + 2 < n) ? ((counts[base + 2] + 7) & ~7) : 0;
    int v3 = (base + 3 < n) ? ((counts[base + 3] + 7) & ~7) : 0;
    tsum[t] = v0 + v1 + v2 + v3;
    __syncthreads();
    for (int d = 1; d < 256; d <<= 1) {
        int x = tsum[t];
        int y = (t >= d) ? tsum[t - d] : 0;
        __syncthreads();
        tsum[t] = x + y;
        __syncthreads();
    }
    int prev = (t > 0) ? tsum[t - 1] : 0;
    if (base + 0 < n) offs[base + 0] = prev;
    if (base + 1 < n) offs[base + 1] = prev + v0;
    if (base + 2 < n) offs[base + 2] = prev + v0 + v1;
    if (base + 3 < n) offs[base + 3] = prev + v0 + v1 + v2;
    if (t == 255) bsums[blockIdx.x] = tsum[255];
}

__global__ void scan_bsums(int* __restrict__ bsums, int nb) {
    __shared__ int s[128];
    int t = threadIdx.x;
    s[t] = (t < nb) ? bsums[t] : 0;
    __syncthreads();
    for (int d = 1; d < 128; d <<= 1) {
        int x = s[t];
        int y = (t >= d) ? s[t - d] : 0;
        __syncthreads();
        s[t] = x + y;
        __syncthreads();
    }
    int excl = (t > 0) ? s[t - 1] : 0;
    if (t < nb) bsums[t] = excl;
}

__global__ void add_base(int* __restrict__ offs, const int* __restrict__ bsums, int n) {
    int i = blockIdx.x * 256 + threadIdx.x;
    if (i < n) offs[i] += bsums[i >> 10];
}

// ---------------- degree counting sort -> perm (similar-degree grouping) ----
__global__ void dhist_kernel(const int* __restrict__ counts, int* __restrict__ bhist,
                             int n) {
    __shared__ int h[64];
    int tid = threadIdx.x;
    if (tid < 64) h[tid] = 0;
    __syncthreads();
#pragma unroll
    for (int k = 0; k < 4; ++k) {
        int i = blockIdx.x * 1024 + tid * 4 + k;
        if (i < n) atomicAdd(&h[min(counts[i], 63)], 1);
    }
    __syncthreads();
    if (tid < 64 && h[tid]) atomicAdd(&bhist[tid], h[tid]);
}

__global__ void dscan_kernel(const int* __restrict__ bhist, int* __restrict__ bcursor) {
    int t = threadIdx.x;  // 64 threads = 1 wave
    int v = bhist[t];
    int s = v;
    for (int d = 1; d < 64; d <<= 1) {
        int y = __shfl_up(s, d);
        if (t >= d) s += y;
    }
    bcursor[t] = s - v;  // exclusive prefix
}

__global__ void dperm_kernel(const int* __restrict__ counts, int* __restrict__ bcursor,
                             int* __restrict__ perm, int n) {
    __shared__ int h[64], base[64], cur[64];
    int tid = threadIdx.x;
    if (tid < 64) { h[tid] = 0; cur[tid] = 0; }
    __syncthreads();
    int bkt[4];
#pragma unroll
    for (int k = 0; k < 4; ++k) {
        int i = blockIdx.x * 1024 + tid * 4 + k;
        bkt[k] = (i < n) ? min(counts[i], 63) : -1;
        if (bkt[k] >= 0) atomicAdd(&h[bkt[k]], 1);
    }
    __syncthreads();
    if (tid < 64 && h[tid] > 0) base[tid] = atomicAdd(&bcursor[tid], h[tid]);
    __syncthreads();
#pragma unroll
    for (int k = 0; k < 4; ++k) {
        if (bkt[k] >= 0) {
            int r = atomicAdd(&cur[bkt[k]], 1);
            perm[base[bkt[k]] + r] = blockIdx.x * 1024 + tid * 4 + k;
        }
    }
}

// ---------------- phase 2b: bucket-local CSR fill (LDS cursors) -------------
__global__ __launch_bounds__(512) void fill2_kernel(
        const unsigned* __restrict__ bedge, const int* __restrict__ bcur,
        const int* __restrict__ offs, int* __restrict__ csrc, int n) {
    __shared__ int lofs[512];
    __shared__ int lcur[512];
    int b = blockIdx.x;
    int tid = threadIdx.x;
    int node = b * 512 + tid;
    lofs[tid] = (node < n) ? offs[node] : 0;
    lcur[tid] = 0;
    __syncthreads();
    int cnt = min(bcur[b], CAPB);
    const unsigned* e = bedge + (size_t)b * CAPB;
    for (int i = tid; i < cnt; i += 512) {
        unsigned pk = e[i];
        int dl = pk >> 17;
        int p = lofs[dl] + atomicAdd(&lcur[dl], 1);
        csrc[p] = (int)(pk & 0x1FFFFu);
    }
}

// fill pad tail of each segment with dummy node N (dis[N]=0 -> zero contribution)
__global__ void pad_kernel(const int* __restrict__ offs, const int* __restrict__ counts,
                           int* __restrict__ csrc, int n) {
    int i = blockIdx.x * 256 + threadIdx.x;
    if (i >= n) return;
    int c = counts[i];
    int p = (c + 7) & ~7;
    int o = offs[i];
    for (int j = c; j < p; ++j) csrc[o + j] = NNODES;
}

// zero dummy row N of gatherable buffers (row-major). Pad gathers read row N
// with norm 0 but fmaf(0, NaN)=NaN, so the row must be finite. Runs AFTER
// fill2 (hB aliases bedge).
__global__ void zdum_kernel(_Float16* __restrict__ x16, _Float16* __restrict__ hA,
                            _Float16* __restrict__ hB, int n) {
    int t = threadIdx.x;  // one block, 320 threads used
    if (t < 64) x16[(size_t)n * 64 + t] = (_Float16)0.f;
    else if (t < 192) hA[(size_t)n * 128 + (t - 64)] = (_Float16)0.f;
    else if (t < 320) hB[(size_t)n * 128 + (t - 192)] = (_Float16)0.f;
}

// x fp32 [N][50] -> fp16 [N][64] zero-padded (aligned gather + K=64 GEMM)
__global__ void cast_pad_kernel(const float* __restrict__ src, _Float16* __restrict__ dst,
                                int n) {
    int t = blockIdx.x * 256 + threadIdx.x;
    if (t >= n * 32) return;
    int node = t >> 5;
    int cp = t & 31;
    int c = cp * 2;
    float v0 = (c < 50) ? src[(size_t)node * 50 + c] : 0.f;
    float v1 = (c + 1 < 50) ? src[(size_t)node * 50 + c + 1] : 0.f;
    f16x2 h;
    h.x = (_Float16)v0;
    h.y = (_Float16)v1;
    *(f16x2*)&dst[(size_t)node * 64 + c] = h;
}

// ---------------- W -> per-lane fragment order (fp16), once per launch ------
__global__ void wfrag_kernel(const float* __restrict__ W, f16x8* __restrict__ frag,
                             int FIN, int FOUT, int KCN, int CTN) {
    int idx = blockIdx.x * 256 + threadIdx.x;
    int tot = KCN * CTN * 64;
    if (idx >= tot) return;
    int lane = idx & 63;
    int ct = (idx >> 6) % CTN;
    int kc = (idx >> 6) / CTN;
    int c = ct * 16 + (lane & 15);
    int kb = kc * 32 + (lane >> 4) * 8;
    f16x8 v;
#pragma unroll
    for (int j = 0; j < 8; ++j) {
        int k = kb + j;
        float w = (k < FIN && c < FOUT) ? W[(size_t)k * FOUT + c] : 0.f;
        v[j] = (_Float16)w;
    }
    frag[idx] = v;
}

// ---------------- fused aggregate + MFMA GEMM + bias + activation -----------
// Block = 16 consecutive DEGREE-SORTED entries of perm (4 waves x 4 nodes).
// 4-node interleaved gather (32 rows in flight); sorted order makes the 4
// lists near-equal length so the pmax loop has ~no waste. XOR-swizzled 16xK
// LDS tile + per-wave 2-column-tile MFMA GEMM; output rows scattered via
// pnode[]. Per-node accumulation order unchanged -> same numerics.
// ACT: 0=relu, 1=sigmoid.
template <int KCN, int ACT, typename OT>
__global__ __launch_bounds__(256, 4) void fused_kernel(
        const f16x2* __restrict__ in, const int* __restrict__ offs,
        const int* __restrict__ counts, const int* __restrict__ csrc,
        const float* __restrict__ dis, const int* __restrict__ perm,
        const f16x8* __restrict__ wfrag, const float* __restrict__ bias,
        int fout, OT* __restrict__ out, int ldo, int n) {
    constexpr int K = KCN * 32;
    constexpr int ROWB = K * 2;   // bytes per LDS row
    constexpr int HW = K / 2;     // f16x2 per row
    __shared__ __align__(16) unsigned char sA[16 * ROWB];
    __shared__ int pnode[16];
    int tid = threadIdx.x;
    int wv = tid >> 6, lane = tid & 63;
    int nb = blockIdx.x * 16;
    bool act = lane < HW;
    if (tid < 16) pnode[tid] = perm[nb + tid];

    int node[4];
    float dd[4], ax[4], ay[4];
    int off[4], pc[4];
#pragma unroll
    for (int k = 0; k < 4; ++k) {
        node[k] = perm[nb + wv * 4 + k];
        dd[k] = dis[node[k]];
        off[k] = offs[node[k]];
        pc[k] = (counts[node[k]] + 7) & ~7;
        ax[k] = 0.f;
        ay[k] = 0.f;
        if (act) {
            f16x2 sv = in[(size_t)node[k] * HW + lane];
            ax[k] = dd[k] * dd[k] * (float)sv.x;
            ay[k] = dd[k] * dd[k] * (float)sv.y;
        }
    }
    int pmax = max(max(pc[0], pc[1]), max(pc[2], pc[3]));

    for (int j = 0; j < pmax; j += 8) {
        int4 i0[4], i1[4];
        float m[4];
#pragma unroll
        for (int k = 0; k < 4; ++k) {
            bool g = j < pc[k];
            int b = off[k] + (g ? j : 0);   // !g: re-read group 0, norm=0
            m[k] = g ? dd[k] : 0.f;
            i0[k] = *(const int4*)&csrc[b];
            i1[k] = *(const int4*)&csrc[b + 4];
        }
#pragma unroll
        for (int k = 0; k < 4; ++k) {
            float u0 = dis[i0[k].x] * m[k], u1 = dis[i0[k].y] * m[k];
            float u2 = dis[i0[k].z] * m[k], u3 = dis[i0[k].w] * m[k];
            float u4 = dis[i1[k].x] * m[k], u5 = dis[i1[k].y] * m[k];
            float u6 = dis[i1[k].z] * m[k], u7 = dis[i1[k].w] * m[k];
            if (act) {
                f16x2 r0 = in[(size_t)i0[k].x * HW + lane];
                f16x2 r1 = in[(size_t)i0[k].y * HW + lane];
                f16x2 r2 = in[(size_t)i0[k].z * HW + lane];
                f16x2 r3 = in[(size_t)i0[k].w * HW + lane];
                f16x2 r4 = in[(size_t)i1[k].x * HW + lane];
                f16x2 r5 = in[(size_t)i1[k].y * HW + lane];
                f16x2 r6 = in[(size_t)i1[k].z * HW + lane];
                f16x2 r7 = in[(size_t)i1[k].w * HW + lane];
                ax[k] = fmaf(u0, (float)r0.x, ax[k]); ay[k] = fmaf(u0, (float)r0.y, ay[k]);
                ax[k] = fmaf(u1, (float)r1.x, ax[k]); ay[k] = fmaf(u1, (float)r1.y, ay[k]);
                ax[k] = fmaf(u2, (float)r2.x, ax[k]); ay[k] = fmaf(u2, (float)r2.y, ay[k]);
                ax[k] = fmaf(u3, (float)r3.x, ax[k]); ay[k] = fmaf(u3, (float)r3.y, ay[k]);
                ax[k] = fmaf(u4, (float)r4.x, ax[k]); ay[k] = fmaf(u4, (float)r4.y, ay[k]);
                ax[k] = fmaf(u5, (float)r5.x, ax[k]); ay[k] = fmaf(u5, (float)r5.y, ay[k]);
                ax[k] = fmaf(u6, (float)r6.x, ax[k]); ay[k] = fmaf(u6, (float)r6.y, ay[k]);
                ax[k] = fmaf(u7, (float)r7.x, ax[k]); ay[k] = fmaf(u7, (float)r7.y, ay[k]);
            }
        }
    }

    if (act) {
#pragma unroll
        for (int k = 0; k < 4; ++k) {
            int r = wv * 4 + k;
            f16x2 o;
            o.x = (_Float16)ax[k];
            o.y = (_Float16)ay[k];
            *(f16x2*)(sA + r * ROWB + ((lane * 4) ^ ((r & 7) << 4))) = o;
        }
    }
    __syncthreads();

    // ---- phase 2: GEMM (per-wave 2 column tiles of 16) ----
    int r = lane & 15, g = lane >> 4;
    f32x4 acc[2];
    acc[0] = (f32x4){0.f, 0.f, 0.f, 0.f};
    acc[1] = (f32x4){0.f, 0.f, 0.f, 0.f};
#pragma unroll
    for (int kc = 0; kc < KCN; ++kc) {
        f16x8 a = *(const f16x8*)(sA + r * ROWB + ((kc * 64 + g * 16) ^ ((r & 7) << 4)));
        f16x8 b0 = wfrag[(size_t)(kc * 8 + wv * 2 + 0) * 64 + lane];
        f16x8 b1 = wfrag[(size_t)(kc * 8 + wv * 2 + 1) * 64 + lane];
        acc[0] = __builtin_amdgcn_mfma_f32_16x16x32_f16(a, b0, acc[0], 0, 0, 0);
        acc[1] = __builtin_amdgcn_mfma_f32_16x16x32_f16(a, b1, acc[1], 0, 0, 0);
    }
#pragma unroll
    for (int c = 0; c < 2; ++c) {
        int col = (wv * 2 + c) * 16 + r;
        if (col >= fout) continue;
        float bv = bias[col];
#pragma unroll
        for (int q = 0; q < 4; ++q) {
            int orow = pnode[g * 4 + q];
            float v = acc[c][q] + bv;
            if (ACT == 0) v = fmaxf(v, 0.f);
            else v = 1.f / (1.f + __expf(-v));
            out[(size_t)orow * ldo + col] = (OT)v;
        }
    }
}

extern "C" void kernel_launch(void* const* d_in, const int* in_sizes, int n_in,
                              void* d_out, int out_size, void* d_ws, size_t ws_size,
                              hipStream_t stream) {
    const float* x = (const float*)d_in[0];
    const int* eidx = (const int*)d_in[1];
    const float* W1 = (const float*)d_in[2];
    const float* b1 = (const float*)d_in[3];
    const float* W2 = (const float*)d_in[4];
    const float* b2 = (const float*)d_in[5];
    const float* W3 = (const float*)d_in[6];
    const float* b3 = (const float*)d_in[7];
    const float* W4 = (const float*)d_in[8];
    const float* b4 = (const float*)d_in[9];
    float* out = (float*)d_out;

    const int N = NNODES;
    const int E = in_sizes[1] / 2;
    const size_t PE = (size_t)E + 8u * N;

    char* ws = (char*)d_ws;
    size_t off = 0;
    auto alloc = [&](size_t bytes) -> char* {
        char* p = ws + off;
        off = (off + bytes + 255) & ~(size_t)255;
        return p;
    };
    float* dis = (float*)alloc((size_t)(N + 1) * 4);
    int* counts = (int*)alloc((size_t)N * 4);
    int* offs = (int*)alloc((size_t)N * 4);
    int* perm = (int*)alloc((size_t)N * 4);
    int* bsums = (int*)alloc(128 * 4);
    int* bcur = (int*)alloc(256 * 4);
    int* bhist = (int*)alloc(64 * 4);
    int* bcursor = (int*)alloc(64 * 4);
    int* csrc = (int*)alloc(PE * 4);
    _Float16* hA = (_Float16*)alloc((size_t)(N + 1) * 128 * 2);
    _Float16* hB = (_Float16*)alloc((size_t)(N + 1) * 128 * 2);
    _Float16* x16 = (_Float16*)alloc((size_t)(N + 1) * 64 * 2);
    f16x8* wf1 = (f16x8*)alloc((size_t)2 * 8 * 64 * 16);
    f16x8* wf2 = (f16x8*)alloc((size_t)4 * 8 * 64 * 16);
    f16x8* wf3 = (f16x8*)alloc((size_t)4 * 8 * 64 * 16);
    f16x8* wf4 = (f16x8*)alloc((size_t)4 * 8 * 64 * 16);
    // bedge aliases hB: dead after fill2; hB fully rewritten by layer-2 GEMM
    // and its dummy row re-zeroed by zdum after fill2.
    unsigned* bedge = (unsigned*)hB;  // NBKT*CAPB*4 ~= 8MB < 25.6MB

    hipMemsetAsync(bcur, 0, 256 * 4, stream);
    hipMemsetAsync(bhist, 0, 64 * 4, stream);

    // weight fragments (once per launch)
    wfrag_kernel<<<(2 * 8 * 64 + 255) / 256, 256, 0, stream>>>(W1, wf1, 50, 128, 2, 8);
    wfrag_kernel<<<(4 * 8 * 64 + 255) / 256, 256, 0, stream>>>(W2, wf2, 128, 128, 4, 8);
    wfrag_kernel<<<(4 * 8 * 64 + 255) / 256, 256, 0, stream>>>(W3, wf3, 128, 128, 4, 8);
    wfrag_kernel<<<(4 * 8 * 64 + 255) / 256, 256, 0, stream>>>(W4, wf4, 128, 121, 4, 8);

    // CSR build
    bin_kernel<<<(E + CHUNK - 1) / CHUNK, 256, 0, stream>>>(eidx, E, bedge, bcur);
    count2_kernel<<<NBKT, 512, 0, stream>>>(bedge, bcur, counts, N);
    dis_kernel<<<(N + 256) / 256, 256, 0, stream>>>(counts, dis, N);
    int nb = (N + 1023) / 1024;
    // degree counting sort -> perm
    dhist_kernel<<<nb, 256, 0, stream>>>(counts, bhist, N);
    dscan_kernel<<<1, 64, 0, stream>>>(bhist, bcursor);
    dperm_kernel<<<nb, 256, 0, stream>>>(counts, bcursor, perm, N);
    // CSR offsets + fill
    scan_local<<<nb, 256, 0, stream>>>(counts, offs, bsums, N);
    scan_bsums<<<1, 128, 0, stream>>>(bsums, nb);
    add_base<<<(N + 255) / 256, 256, 0, stream>>>(offs, bsums, N);
    fill2_kernel<<<NBKT, 512, 0, stream>>>(bedge, bcur, offs, csrc, N);
    pad_kernel<<<(N + 255) / 256, 256, 0, stream>>>(offs, counts, csrc, N);
    zdum_kernel<<<1, 320, 0, stream>>>(x16, hA, hB, N);  // after fill2 (bedge dead)

    cast_pad_kernel<<<(N * 32 + 255) / 256, 256, 0, stream>>>(x, x16, N);

    int fblocks = N / 16;  // 6250 blocks; block = 16 sorted nodes, 4 waves
    // layer 1: fused agg(50->64-pad) + GEMM 64->128 + relu -> hA
    fused_kernel<2, 0, _Float16><<<fblocks, 256, 0, stream>>>(
        (const f16x2*)x16, offs, counts, csrc, dis, perm, wf1, b1, 128, hA, 128, N);
    // layer 2: hA -> hB
    fused_kernel<4, 0, _Float16><<<fblocks, 256, 0, stream>>>(
        (const f16x2*)hA, offs, counts, csrc, dis, perm, wf2, b2, 128, hB, 128, N);
    // layer 3: hB -> hA
    fused_kernel<4, 0, _Float16><<<fblocks, 256, 0, stream>>>(
        (const f16x2*)hB, offs, counts, csrc, dis, perm, wf3, b3, 128, hA, 128, N);
    // layer 4: hA -> d_out (sigmoid, fp32, 121 cols)
    fused_kernel<4, 1, float><<<fblocks, 256, 0, stream>>>(
        (const f16x2*)hA, offs, counts, csrc, dis, perm, wf4, b4, 121, out, 121, N);
}

// Round 15
// 378.028 us; speedup vs baseline: 1.4025x; 1.3479x over previous
//
#include <hip/hip_runtime.h>
#include <math.h>

#define NNODES 100000
#define BSHIFT 9
#define NBKT ((NNODES + (1 << BSHIFT) - 1) >> BSHIFT)   // 196 buckets of 512 nodes
#define CAPB 10240                                       // expected 8163 + 23 sigma
#define CHUNK 2048

typedef _Float16 f16x8 __attribute__((ext_vector_type(8)));
typedef _Float16 f16x2 __attribute__((ext_vector_type(2)));
typedef float f32x4 __attribute__((ext_vector_type(4)));

// ---------------- phase 1: bin edges by dst bucket (packed 4B/edge) ---------
// packed = (dst&511)<<17 | src   (src < 2^17)
__global__ __launch_bounds__(256) void bin_kernel(
        const int* __restrict__ eidx, int E,
        unsigned* __restrict__ bedge, int* __restrict__ bcur) {
    __shared__ int hist[256];
    __shared__ int scanx[256];
    __shared__ int gbase[256];
    __shared__ unsigned stage[CHUNK];
    int tid = threadIdx.x;
    int base = blockIdx.x * CHUNK;
    if (base >= E) return;
    int m = min(CHUNK, E - base);
    hist[tid] = 0;
    __syncthreads();
    unsigned pk[8];
    int b[8], r[8];
#pragma unroll
    for (int j = 0; j < 8; ++j) {
        int rel = j * 256 + tid;
        bool ok = rel < m;
        int e = base + (ok ? rel : 0);
        int s = eidx[e];
        int d = eidx[E + e];
        b[j] = d >> BSHIFT;
        pk[j] = ((unsigned)(d & ((1 << BSHIFT) - 1)) << 17) | (unsigned)s;
        r[j] = ok ? atomicAdd(&hist[b[j]], 1) : -1;
    }
    __syncthreads();
    int h = hist[tid];
    scanx[tid] = h;
    __syncthreads();
    for (int st = 1; st < 256; st <<= 1) {
        int y = (tid >= st) ? scanx[tid - st] : 0;
        __syncthreads();
        scanx[tid] += y;
        __syncthreads();
    }
    int excl = scanx[tid] - h;
    if (h > 0) gbase[tid] = atomicAdd(&bcur[tid], h);
    __syncthreads();
    scanx[tid] = excl;
    __syncthreads();
#pragma unroll
    for (int j = 0; j < 8; ++j)
        if (r[j] >= 0) stage[scanx[b[j]] + r[j]] = pk[j];
    __syncthreads();
    for (int i = tid; i < m; i += 256) {
        int lo = 0, hi = NBKT - 1;
        while (lo < hi) {
            int mid = (lo + hi + 1) >> 1;
            if (scanx[mid] <= i) lo = mid; else hi = mid - 1;
        }
        int idx = gbase[lo] + (i - scanx[lo]);
        if (idx < CAPB) bedge[(size_t)lo * CAPB + idx] = stage[i];
    }
}

// ---------------- phase 2a: per-node counts from binned edges ---------------
__global__ __launch_bounds__(512) void count2_kernel(
        const unsigned* __restrict__ bedge, const int* __restrict__ bcur,
        int* __restrict__ counts, int n) {
    __shared__ int h[512];
    int b = blockIdx.x;
    int tid = threadIdx.x;
    h[tid] = 0;
    __syncthreads();
    int cnt = min(bcur[b], CAPB);
    const unsigned* e = bedge + (size_t)b * CAPB;
    for (int i = tid; i < cnt; i += 512) atomicAdd(&h[e[i] >> 17], 1);
    __syncthreads();
    int node = b * 512 + tid;
    if (node < n) counts[node] = h[tid];
}

// dis[i] = rsqrt(deg+1) for i<n; dis[n] = 0 (dummy node for pad slots)
__global__ void dis_kernel(const int* __restrict__ counts, float* __restrict__ dis, int n) {
    int i = blockIdx.x * 256 + threadIdx.x;
    if (i < n) dis[i] = rsqrtf((float)(counts[i] + 1));
    else if (i == n) dis[i] = 0.f;
}

// exclusive scan of PADDED counts -> offs; 1024 elements per block
__global__ void scan_local(const int* __restrict__ counts, int* __restrict__ offs,
                           int* __restrict__ bsums, int n) {
    __shared__ int tsum[256];
    int t = threadIdx.x;
    int base = blockIdx.x * 1024 + t * 4;
    int v0 = (base + 0 < n) ? ((counts[base + 0] + 7) & ~7) : 0;
    int v1 = (base + 1 < n) ? ((counts[base + 1] + 7) & ~7) : 0;
    int v2 = (base + 2 < n) ? ((counts[base + 2] + 7) & ~7) : 0;
    int v3 = (base + 3 < n) ? ((counts[base + 3] + 7) & ~7) : 0;
    tsum[t] = v0 + v1 + v2 + v3;
    __syncthreads();
    for (int d = 1; d < 256; d <<= 1) {
        int x = tsum[t];
        int y = (t >= d) ? tsum[t - d] : 0;
        __syncthreads();
        tsum[t] = x + y;
        __syncthreads();
    }
    int prev = (t > 0) ? tsum[t - 1] : 0;
    if (base + 0 < n) offs[base + 0] = prev;
    if (base + 1 < n) offs[base + 1] = prev + v0;
    if (base + 2 < n) offs[base + 2] = prev + v0 + v1;
    if (base + 3 < n) offs[base + 3] = prev + v0 + v1 + v2;
    if (t == 255) bsums[blockIdx.x] = tsum[255];
}

__global__ void scan_bsums(int* __restrict__ bsums, int nb) {
    __shared__ int s[128];
    int t = threadIdx.x;
    s[t] = (t < nb) ? bsums[t] : 0;
    __syncthreads();
    for (int d = 1; d < 128; d <<= 1) {
        int x = s[t];
        int y = (t >= d) ? s[t - d] : 0;
        __syncthreads();
        s[t] = x + y;
        __syncthreads();
    }
    int excl = (t > 0) ? s[t - 1] : 0;
    if (t < nb) bsums[t] = excl;
}

__global__ void add_base(int* __restrict__ offs, const int* __restrict__ bsums, int n) {
    int i = blockIdx.x * 256 + threadIdx.x;
    if (i < n) offs[i] += bsums[i >> 10];
}

// ---------------- phase 2b: bucket-local CSR fill (LDS cursors) -------------
__global__ __launch_bounds__(512) void fill2_kernel(
        const unsigned* __restrict__ bedge, const int* __restrict__ bcur,
        const int* __restrict__ offs, int* __restrict__ csrc, int n) {
    __shared__ int lofs[512];
    __shared__ int lcur[512];
    int b = blockIdx.x;
    int tid = threadIdx.x;
    int node = b * 512 + tid;
    lofs[tid] = (node < n) ? offs[node] : 0;
    lcur[tid] = 0;
    __syncthreads();
    int cnt = min(bcur[b], CAPB);
    const unsigned* e = bedge + (size_t)b * CAPB;
    for (int i = tid; i < cnt; i += 512) {
        unsigned pk = e[i];
        int dl = pk >> 17;
        int p = lofs[dl] + atomicAdd(&lcur[dl], 1);
        csrc[p] = (int)(pk & 0x1FFFFu);
    }
}

// fill pad tail of each segment with dummy node N (dis[N]=0 -> zero contribution)
__global__ void pad_kernel(const int* __restrict__ offs, const int* __restrict__ counts,
                           int* __restrict__ csrc, int n) {
    int i = blockIdx.x * 256 + threadIdx.x;
    if (i >= n) return;
    int c = counts[i];
    int p = (c + 7) & ~7;
    int o = offs[i];
    for (int j = c; j < p; ++j) csrc[o + j] = NNODES;
}

// zero dummy row N of gatherable buffers (row-major). Pad gathers read row N
// with norm 0 but fmaf(0, NaN)=NaN, so the row must be finite. Runs AFTER
// fill2 (hB aliases bedge).
__global__ void zdum_kernel(_Float16* __restrict__ x16, _Float16* __restrict__ hA,
                            _Float16* __restrict__ hB, int n) {
    int t = threadIdx.x;  // one block, 320 threads used
    if (t < 64) x16[(size_t)n * 64 + t] = (_Float16)0.f;
    else if (t < 192) hA[(size_t)n * 128 + (t - 64)] = (_Float16)0.f;
    else if (t < 320) hB[(size_t)n * 128 + (t - 192)] = (_Float16)0.f;
}

// x fp32 [N][50] -> fp16 [N][64] zero-padded (aligned gather + K=64 GEMM)
__global__ void cast_pad_kernel(const float* __restrict__ src, _Float16* __restrict__ dst,
                                int n) {
    int t = blockIdx.x * 256 + threadIdx.x;
    if (t >= n * 32) return;
    int node = t >> 5;
    int cp = t & 31;
    int c = cp * 2;
    float v0 = (c < 50) ? src[(size_t)node * 50 + c] : 0.f;
    float v1 = (c + 1 < 50) ? src[(size_t)node * 50 + c + 1] : 0.f;
    f16x2 h;
    h.x = (_Float16)v0;
    h.y = (_Float16)v1;
    *(f16x2*)&dst[(size_t)node * 64 + c] = h;
}

// ---------------- W -> per-lane fragment order (fp16), once per launch ------
__global__ void wfrag_kernel(const float* __restrict__ W, f16x8* __restrict__ frag,
                             int FIN, int FOUT, int KCN, int CTN) {
    int idx = blockIdx.x * 256 + threadIdx.x;
    int tot = KCN * CTN * 64;
    if (idx >= tot) return;
    int lane = idx & 63;
    int ct = (idx >> 6) % CTN;
    int kc = (idx >> 6) / CTN;
    int c = ct * 16 + (lane & 15);
    int kb = kc * 32 + (lane >> 4) * 8;
    f16x8 v;
#pragma unroll
    for (int j = 0; j < 8; ++j) {
        int k = kb + j;
        float w = (k < FIN && c < FOUT) ? W[(size_t)k * FOUT + c] : 0.f;
        v[j] = (_Float16)w;
    }
    frag[idx] = v;
}

// ---------------- fused aggregate + MFMA GEMM + bias + activation -----------
// Round-8 structure (best measured: 81us/layer, 378us total). Block = 16
// nodes, 4 waves. Phase 1: wave aggregates its 4 nodes sequentially (8
// row-gathers in flight; fp32 accum -> fp16) into an XOR-swizzled 16xK LDS
// tile (byte ^= (row&7)<<4). Phase 2 after one barrier: per wave KCNx2 MFMAs
// (16x16x32 f16) + bias/act + direct store. Requires n % 16 == 0.
// ACT: 0=relu, 1=sigmoid.
template <int KCN, int ACT, typename OT>
__global__ __launch_bounds__(256) void fused_kernel(
        const f16x2* __restrict__ in, const int* __restrict__ offs,
        const int* __restrict__ counts, const int* __restrict__ csrc,
        const float* __restrict__ dis, const f16x8* __restrict__ wfrag,
        const float* __restrict__ bias, int fout,
        OT* __restrict__ out, int ldo, int n) {
    constexpr int K = KCN * 32;
    constexpr int ROWB = K * 2;   // bytes per LDS row
    constexpr int HW = K / 2;     // f16x2 per row
    __shared__ __align__(16) unsigned char sA[16 * ROWB];
    int tid = threadIdx.x;
    int wv = tid >> 6, lane = tid & 63;
    int nb = blockIdx.x * 16;
    bool act = lane < HW;

#pragma unroll 1
    for (int s = 0; s < 4; ++s) {
        int node = nb + wv * 4 + s;
        float dd = dis[node];
        float a0 = 0.f, a1 = 0.f;
        if (act) {
            f16x2 self = in[(size_t)node * HW + lane];
            a0 = dd * dd * (float)self.x;
            a1 = dd * dd * (float)self.y;
        }
        int off = offs[node];
        int pcnt = (counts[node] + 7) & ~7;
        for (int j = 0; j < pcnt; j += 8) {
            int4 s0 = *(const int4*)&csrc[off + j];
            int4 s1 = *(const int4*)&csrc[off + j + 4];
            float v0 = dis[s0.x] * dd, v1 = dis[s0.y] * dd;
            float v2 = dis[s0.z] * dd, v3 = dis[s0.w] * dd;
            float v4 = dis[s1.x] * dd, v5 = dis[s1.y] * dd;
            float v6 = dis[s1.z] * dd, v7 = dis[s1.w] * dd;
            if (act) {
                f16x2 r0 = in[(size_t)s0.x * HW + lane];
                f16x2 r1 = in[(size_t)s0.y * HW + lane];
                f16x2 r2 = in[(size_t)s0.z * HW + lane];
                f16x2 r3 = in[(size_t)s0.w * HW + lane];
                f16x2 r4 = in[(size_t)s1.x * HW + lane];
                f16x2 r5 = in[(size_t)s1.y * HW + lane];
                f16x2 r6 = in[(size_t)s1.z * HW + lane];
                f16x2 r7 = in[(size_t)s1.w * HW + lane];
                a0 = fmaf(v0, (float)r0.x, a0); a1 = fmaf(v0, (float)r0.y, a1);
                a0 = fmaf(v1, (float)r1.x, a0); a1 = fmaf(v1, (float)r1.y, a1);
                a0 = fmaf(v2, (float)r2.x, a0); a1 = fmaf(v2, (float)r2.y, a1);
                a0 = fmaf(v3, (float)r3.x, a0); a1 = fmaf(v3, (float)r3.y, a1);
                a0 = fmaf(v4, (float)r4.x, a0); a1 = fmaf(v4, (float)r4.y, a1);
                a0 = fmaf(v5, (float)r5.x, a0); a1 = fmaf(v5, (float)r5.y, a1);
                a0 = fmaf(v6, (float)r6.x, a0); a1 = fmaf(v6, (float)r6.y, a1);
                a0 = fmaf(v7, (float)r7.x, a0); a1 = fmaf(v7, (float)r7.y, a1);
            }
        }
        int r = wv * 4 + s;
        if (act) {
            f16x2 o;
            o.x = (_Float16)a0;
            o.y = (_Float16)a1;
            *(f16x2*)(sA + r * ROWB + ((lane * 4) ^ ((r & 7) << 4))) = o;
        }
    }
    __syncthreads();

    // ---- phase 2: GEMM (per-wave 2 column tiles of 16) ----
    int r = lane & 15, g = lane >> 4;
    f32x4 acc[2];
    acc[0] = (f32x4){0.f, 0.f, 0.f, 0.f};
    acc[1] = (f32x4){0.f, 0.f, 0.f, 0.f};
#pragma unroll
    for (int kc = 0; kc < KCN; ++kc) {
        f16x8 a = *(const f16x8*)(sA + r * ROWB + ((kc * 64 + g * 16) ^ ((r & 7) << 4)));
        f16x8 b0 = wfrag[(size_t)(kc * 8 + wv * 2 + 0) * 64 + lane];
        f16x8 b1 = wfrag[(size_t)(kc * 8 + wv * 2 + 1) * 64 + lane];
        acc[0] = __builtin_amdgcn_mfma_f32_16x16x32_f16(a, b0, acc[0], 0, 0, 0);
        acc[1] = __builtin_amdgcn_mfma_f32_16x16x32_f16(a, b1, acc[1], 0, 0, 0);
    }
#pragma unroll
    for (int c = 0; c < 2; ++c) {
        int col = (wv * 2 + c) * 16 + r;
        if (col >= fout) continue;
        float bv = bias[col];
#pragma unroll
        for (int q = 0; q < 4; ++q) {
            int orow = nb + g * 4 + q;
            float v = acc[c][q] + bv;
            if (ACT == 0) v = fmaxf(v, 0.f);
            else v = 1.f / (1.f + __expf(-v));
            out[(size_t)orow * ldo + col] = (OT)v;
        }
    }
}

extern "C" void kernel_launch(void* const* d_in, const int* in_sizes, int n_in,
                              void* d_out, int out_size, void* d_ws, size_t ws_size,
                              hipStream_t stream) {
    const float* x = (const float*)d_in[0];
    const int* eidx = (const int*)d_in[1];
    const float* W1 = (const float*)d_in[2];
    const float* b1 = (const float*)d_in[3];
    const float* W2 = (const float*)d_in[4];
    const float* b2 = (const float*)d_in[5];
    const float* W3 = (const float*)d_in[6];
    const float* b3 = (const float*)d_in[7];
    const float* W4 = (const float*)d_in[8];
    const float* b4 = (const float*)d_in[9];
    float* out = (float*)d_out;

    const int N = NNODES;
    const int E = in_sizes[1] / 2;
    const size_t PE = (size_t)E + 8u * N;

    char* ws = (char*)d_ws;
    size_t off = 0;
    auto alloc = [&](size_t bytes) -> char* {
        char* p = ws + off;
        off = (off + bytes + 255) & ~(size_t)255;
        return p;
    };
    float* dis = (float*)alloc((size_t)(N + 1) * 4);
    int* counts = (int*)alloc((size_t)N * 4);
    int* offs = (int*)alloc((size_t)N * 4);
    int* bsums = (int*)alloc(128 * 4);
    int* bcur = (int*)alloc(256 * 4);
    int* csrc = (int*)alloc(PE * 4);
    _Float16* hA = (_Float16*)alloc((size_t)(N + 1) * 128 * 2);
    _Float16* hB = (_Float16*)alloc((size_t)(N + 1) * 128 * 2);
    _Float16* x16 = (_Float16*)alloc((size_t)(N + 1) * 64 * 2);
    f16x8* wf1 = (f16x8*)alloc((size_t)2 * 8 * 64 * 16);
    f16x8* wf2 = (f16x8*)alloc((size_t)4 * 8 * 64 * 16);
    f16x8* wf3 = (f16x8*)alloc((size_t)4 * 8 * 64 * 16);
    f16x8* wf4 = (f16x8*)alloc((size_t)4 * 8 * 64 * 16);
    // bedge aliases hB: dead after fill2; hB fully rewritten by layer-2 GEMM
    // and its dummy row re-zeroed by zdum after fill2.
    unsigned* bedge = (unsigned*)hB;  // NBKT*CAPB*4 ~= 8MB < 25.6MB

    hipMemsetAsync(bcur, 0, 256 * 4, stream);

    // weight fragments (once per launch)
    wfrag_kernel<<<(2 * 8 * 64 + 255) / 256, 256, 0, stream>>>(W1, wf1, 50, 128, 2, 8);
    wfrag_kernel<<<(4 * 8 * 64 + 255) / 256, 256, 0, stream>>>(W2, wf2, 128, 128, 4, 8);
    wfrag_kernel<<<(4 * 8 * 64 + 255) / 256, 256, 0, stream>>>(W3, wf3, 128, 128, 4, 8);
    wfrag_kernel<<<(4 * 8 * 64 + 255) / 256, 256, 0, stream>>>(W4, wf4, 128, 121, 4, 8);

    // CSR build
    bin_kernel<<<(E + CHUNK - 1) / CHUNK, 256, 0, stream>>>(eidx, E, bedge, bcur);
    count2_kernel<<<NBKT, 512, 0, stream>>>(bedge, bcur, counts, N);
    dis_kernel<<<(N + 256) / 256, 256, 0, stream>>>(counts, dis, N);
    int nb = (N + 1023) / 1024;
    scan_local<<<nb, 256, 0, stream>>>(counts, offs, bsums, N);
    scan_bsums<<<1, 128, 0, stream>>>(bsums, nb);
    add_base<<<(N + 255) / 256, 256, 0, stream>>>(offs, bsums, N);
    fill2_kernel<<<NBKT, 512, 0, stream>>>(bedge, bcur, offs, csrc, N);
    pad_kernel<<<(N + 255) / 256, 256, 0, stream>>>(offs, counts, csrc, N);
    zdum_kernel<<<1, 320, 0, stream>>>(x16, hA, hB, N);  // after fill2 (bedge dead)

    cast_pad_kernel<<<(N * 32 + 255) / 256, 256, 0, stream>>>(x, x16, N);

    int fblocks = N / 16;  // 6250 blocks; block = 16 nodes, 4 waves
    // layer 1: fused agg(50->64-pad) + GEMM 64->128 + relu -> hA
    fused_kernel<2, 0, _Float16><<<fblocks, 256, 0, stream>>>(
        (const f16x2*)x16, offs, counts, csrc, dis, wf1, b1, 128, hA, 128, N);
    // layer 2: hA -> hB
    fused_kernel<4, 0, _Float16><<<fblocks, 256, 0, stream>>>(
        (const f16x2*)hA, offs, counts, csrc, dis, wf2, b2, 128, hB, 128, N);
    // layer 3: hB -> hA
    fused_kernel<4, 0, _Float16><<<fblocks, 256, 0, stream>>>(
        (const f16x2*)hB, offs, counts, csrc, dis, wf3, b3, 128, hA, 128, N);
    // layer 4: hA -> d_out (sigmoid, fp32, 121 cols)
    fused_kernel<4, 1, float><<<fblocks, 256, 0, stream>>>(
        (const f16x2*)hA, offs, counts, csrc, dis, wf4, b4, 121, out, 121, N);
}